// Round 3
// baseline (2898.014 us; speedup 1.0000x reference)
//
#include <hip/hip_runtime.h>
#include <hip/hip_bf16.h>
#include <math.h>

// Problem constants
#define N_TOK 1024
#define TOPK  2
#define NEXP  16
#define HID   1024   // H
#define DIM   2048   // D
#define RANK  16
#define NPAIR (N_TOK * TOPK)
#define MOE_SCALE 0.25f

typedef __attribute__((ext_vector_type(8))) short short8;
typedef __attribute__((ext_vector_type(4))) float floatx4;

static __device__ __forceinline__ unsigned short f2bf(float f) {
    union { float f; unsigned int u; } v; v.f = f;
    unsigned int u = v.u;
    u += 0x7fffu + ((u >> 16) & 1u);   // RNE
    return (unsigned short)(u >> 16);
}

static __device__ __forceinline__ float bf2f(unsigned short s) {
    union { unsigned int u; float f; } v; v.u = ((unsigned int)s) << 16;
    return v.f;
}

static __device__ __forceinline__ short8 cvt8(float4 a, float4 b) {
    short8 o;
    o[0] = (short)f2bf(a.x); o[1] = (short)f2bf(a.y);
    o[2] = (short)f2bf(a.z); o[3] = (short)f2bf(a.w);
    o[4] = (short)f2bf(b.x); o[5] = (short)f2bf(b.y);
    o[6] = (short)f2bf(b.z); o[7] = (short)f2bf(b.w);
    return o;
}

// ---------------------------------------------------------------------------
// Kernel: routing — sort pair indices by expert. One block.
// ---------------------------------------------------------------------------
__global__ void k_routing(const int* __restrict__ ids,
                          int* __restrict__ offs,      // [NEXP+1]
                          int* __restrict__ sorted) {  // [NPAIR]
    __shared__ int s_cnt[NEXP];
    __shared__ int s_off[NEXP + 1];
    int tid = threadIdx.x;
    if (tid < NEXP) s_cnt[tid] = 0;
    __syncthreads();
    for (int p = tid; p < NPAIR; p += blockDim.x) atomicAdd(&s_cnt[ids[p]], 1);
    __syncthreads();
    if (tid == 0) {
        int acc = 0;
        for (int e = 0; e < NEXP; ++e) { s_off[e] = acc; acc += s_cnt[e]; }
        s_off[NEXP] = acc;
    }
    __syncthreads();
    if (tid <= NEXP) offs[tid] = s_off[tid];
    if (tid < NEXP) s_cnt[tid] = s_off[tid];
    __syncthreads();
    for (int p = tid; p < NPAIR; p += blockDim.x) {
        int e = ids[p];
        int slot = atomicAdd(&s_cnt[e], 1);
        sorted[slot] = p;
    }
}

// ---------------------------------------------------------------------------
// Kernel: t_up[p][r] = SCALE * dot(x[n], up_a[e][r]).  One wave per pair.
// ---------------------------------------------------------------------------
__global__ void k_tup(const float* __restrict__ x, const int* __restrict__ ids,
                      const float* __restrict__ up_a, float* __restrict__ t_up) {
    int p = blockIdx.x;
    int lane = threadIdx.x;
    int n = p / TOPK;
    int e = ids[p];
    const float* xr = x + (size_t)n * DIM;
    const float* ar = up_a + (size_t)e * RANK * DIM;
    for (int r = 0; r < RANK; ++r) {
        const float* a = ar + (size_t)r * DIM;
        float s = 0.f;
        for (int d = lane; d < DIM; d += 64) s += xr[d] * a[d];
        for (int m = 32; m; m >>= 1) s += __shfl_xor(s, m, 64);
        if (lane == 0) t_up[(size_t)p * RANK + r] = MOE_SCALE * s;
    }
}

// ---------------------------------------------------------------------------
// Kernel: up-GEMM. 128 tokens x 128 cols (64 gate + 64 mul), BK=64.
// A gathered from x (fp32, d_in), B from w_up (fp32, d_in); in-register
// fp32->bf16 convert; register-prefetch of next K-chunk overlaps MFMA.
// Epilogue: LoRA rank-16 + erf-gelu * mul -> act[slot][h] (bf16).
// ---------------------------------------------------------------------------
__global__ __launch_bounds__(256) void k_up(
        const float* __restrict__ x, const float* __restrict__ w_up,
        const float* __restrict__ up_b, const float* __restrict__ t_up,
        const int* __restrict__ offs, const int* __restrict__ sorted,
        unsigned short* __restrict__ act) {
    int e  = blockIdx.x >> 4;
    int mt = blockIdx.x & 15;
    int nt = blockIdx.y;
    int off = offs[e], cnt = offs[e + 1] - off;
    if (mt * 128 >= cnt) return;

    __shared__ unsigned short sA[128 * 64];   // 16 KB, swizzled
    __shared__ unsigned short sB[128 * 64];   // 16 KB, swizzled

    int tid = threadIdx.x, lane = tid & 63, wv = tid >> 6;
    int lm = lane & 15, lq = lane >> 4;

    // staging: 2 threads per row, each 32 fp32 columns (128 B)
    int row  = tid >> 1;          // 0..127
    int hc   = (tid & 1) * 32;    // fp32 col offset within chunk

    int g = mt * 128 + row; if (g >= cnt) g = cnt - 1;   // clamp (dup rows ok)
    int p = sorted[off + g];
    const float* aptr = x + (size_t)(p >> 1) * DIM + hc;

    int wrow = (row < 64) ? (nt * 64 + row) : (HID + nt * 64 + (row - 64));
    const float* bptr = w_up + ((size_t)e * 2 * HID + wrow) * DIM + hc;

    floatx4 acc[2][8];
    floatx4 zero = {0.f, 0.f, 0.f, 0.f};
#pragma unroll
    for (int i = 0; i < 2; ++i)
#pragma unroll
        for (int j = 0; j < 8; ++j) acc[i][j] = zero;

    float4 pa[8], pb[8];
#pragma unroll
    for (int j = 0; j < 8; ++j) {
        pa[j] = *(const float4*)(aptr + 4 * j);
        pb[j] = *(const float4*)(bptr + 4 * j);
    }

    for (int kc = 0; kc < 32; ++kc) {
        // convert staged regs -> LDS (bf16, XOR-8 chunk swizzle)
#pragma unroll
        for (int c = 0; c < 4; ++c) {
            short8 va = cvt8(pa[2 * c], pa[2 * c + 1]);
            short8 vb = cvt8(pb[2 * c], pb[2 * c + 1]);
            int cl = (tid & 1) * 4 + c;
            *(short8*)(sA + row * 64 + ((cl ^ (row & 7)) * 8)) = va;
            *(short8*)(sB + row * 64 + ((cl ^ (row & 7)) * 8)) = vb;
        }
        __syncthreads();
        if (kc + 1 < 32) {   // prefetch next chunk; overlaps MFMA below
            const float* an = aptr + (kc + 1) * 64;
            const float* bn = bptr + (kc + 1) * 64;
#pragma unroll
            for (int j = 0; j < 8; ++j) {
                pa[j] = *(const float4*)(an + 4 * j);
                pb[j] = *(const float4*)(bn + 4 * j);
            }
        }
#pragma unroll
        for (int kk = 0; kk < 2; ++kk) {
            int r0 = wv * 32 + lm;
            int r1 = wv * 32 + 16 + lm;
            short8 af0 = *(const short8*)(sA + r0 * 64 + (((kk * 4 + lq) ^ (r0 & 7)) * 8));
            short8 af1 = *(const short8*)(sA + r1 * 64 + (((kk * 4 + lq) ^ (r1 & 7)) * 8));
#pragma unroll
            for (int n2 = 0; n2 < 8; ++n2) {
                int r = n2 * 16 + lm;
                short8 bf = *(const short8*)(sB + r * 64 + (((kk * 4 + lq) ^ (r & 7)) * 8));
                acc[0][n2] = __builtin_amdgcn_mfma_f32_16x16x32_bf16(af0, bf, acc[0][n2], 0, 0, 0);
                acc[1][n2] = __builtin_amdgcn_mfma_f32_16x16x32_bf16(af1, bf, acc[1][n2], 0, 0, 0);
            }
        }
        __syncthreads();
    }

    // epilogue: LoRA rank-16 + erf-gelu * mul -> act[slot][h]
    const float* upb = up_b + (size_t)e * 2 * HID * RANK;
#pragma unroll
    for (int n2 = 0; n2 < 4; ++n2) {
        int h = nt * 64 + n2 * 16 + lm;
        const float* b1 = upb + (size_t)h * RANK;
        const float* b2 = upb + (size_t)(h + HID) * RANK;
        float r1[RANK], r2[RANK];
#pragma unroll
        for (int i = 0; i < RANK; ++i) { r1[i] = b1[i]; r2[i] = b2[i]; }
#pragma unroll
        for (int i = 0; i < 2; ++i) {
#pragma unroll
            for (int r = 0; r < 4; ++r) {
                int gg = mt * 128 + wv * 32 + i * 16 + lq * 4 + r;
                if (gg < cnt) {
                    int slot = off + gg;
                    int pp = sorted[slot];
                    const float* tv = t_up + (size_t)pp * RANK;
                    float s1 = acc[i][n2][r], s2 = acc[i][n2 + 4][r];
#pragma unroll
                    for (int j = 0; j < RANK; ++j) { s1 += tv[j] * r1[j]; s2 += tv[j] * r2[j]; }
                    float gl = 0.5f * s1 * (1.f + erff(s1 * 0.70710678118654752f));
                    act[(size_t)slot * HID + h] = f2bf(gl * s2);
                }
            }
        }
    }
}

// ---------------------------------------------------------------------------
// Kernel: t2[slot][r] = SCALE * dot(act[slot], down_a[e][r]). One wave/slot.
// ---------------------------------------------------------------------------
__global__ void k_t2(const unsigned short* __restrict__ act,
                     const int* __restrict__ ids, const int* __restrict__ sorted,
                     const float* __restrict__ down_a, float* __restrict__ t2) {
    int s = blockIdx.x;
    int lane = threadIdx.x;
    int p = sorted[s];
    int e = ids[p];
    const unsigned short* ar = act + (size_t)s * HID;
    const float* da = down_a + (size_t)e * RANK * HID;
    float av[16];
#pragma unroll
    for (int i = 0; i < 16; ++i) av[i] = bf2f(ar[lane + i * 64]);
    for (int r = 0; r < RANK; ++r) {
        const float* a = da + (size_t)r * HID;
        float sum = 0.f;
#pragma unroll
        for (int i = 0; i < 16; ++i) sum += av[i] * a[lane + i * 64];
        for (int m = 32; m; m >>= 1) sum += __shfl_xor(sum, m, 64);
        if (lane == 0) t2[(size_t)s * RANK + r] = MOE_SCALE * sum;
    }
}

// ---------------------------------------------------------------------------
// Kernel: down-GEMM. 128 tokens x 128 d-rows, BK=64. A from act (bf16, ws),
// B from w_down (fp32, d_in) with in-register convert + register prefetch.
// Epilogue: LoRA + topk-weight + atomic scatter-add.
// ---------------------------------------------------------------------------
__global__ __launch_bounds__(256) void k_down(
        const unsigned short* __restrict__ act, const float* __restrict__ w_down,
        const int* __restrict__ ids, const float* __restrict__ tw,
        const float* __restrict__ down_b, const float* __restrict__ t2,
        const int* __restrict__ offs, const int* __restrict__ sorted,
        float* __restrict__ out) {
    int e  = blockIdx.x >> 4;
    int mt = blockIdx.x & 15;
    int nt = blockIdx.y;
    int off = offs[e], cnt = offs[e + 1] - off;
    if (mt * 128 >= cnt) return;

    __shared__ unsigned short sA[128 * 64];
    __shared__ unsigned short sB[128 * 64];

    int tid = threadIdx.x, lane = tid & 63, wv = tid >> 6;
    int lm = lane & 15, lq = lane >> 4;

    int row = tid >> 1;           // 0..127
    int hcA = (tid & 1) * 32;     // bf16 col offset (A)
    int hcB = (tid & 1) * 32;     // fp32 col offset (B)

    int g = mt * 128 + row; if (g >= cnt) g = cnt - 1;
    const unsigned short* aptr = act + (size_t)(off + g) * HID + hcA;

    int d = nt * 128 + row;
    const float* bptr = w_down + ((size_t)e * DIM + d) * HID + hcB;

    floatx4 acc[2][8];
    floatx4 zero = {0.f, 0.f, 0.f, 0.f};
#pragma unroll
    for (int i = 0; i < 2; ++i)
#pragma unroll
        for (int j = 0; j < 8; ++j) acc[i][j] = zero;

    short8 pa[4];
    float4 pb[8];
#pragma unroll
    for (int j = 0; j < 4; ++j) pa[j] = *(const short8*)(aptr + 8 * j);
#pragma unroll
    for (int j = 0; j < 8; ++j) pb[j] = *(const float4*)(bptr + 4 * j);

    for (int kc = 0; kc < 16; ++kc) {
#pragma unroll
        for (int c = 0; c < 4; ++c) {
            short8 vb = cvt8(pb[2 * c], pb[2 * c + 1]);
            int cl = (tid & 1) * 4 + c;
            *(short8*)(sA + row * 64 + ((cl ^ (row & 7)) * 8)) = pa[c];
            *(short8*)(sB + row * 64 + ((cl ^ (row & 7)) * 8)) = vb;
        }
        __syncthreads();
        if (kc + 1 < 16) {
            const unsigned short* an = aptr + (kc + 1) * 64;
            const float* bn = bptr + (kc + 1) * 64;
#pragma unroll
            for (int j = 0; j < 4; ++j) pa[j] = *(const short8*)(an + 8 * j);
#pragma unroll
            for (int j = 0; j < 8; ++j) pb[j] = *(const float4*)(bn + 4 * j);
        }
#pragma unroll
        for (int kk = 0; kk < 2; ++kk) {
            int r0 = wv * 32 + lm;
            int r1 = wv * 32 + 16 + lm;
            short8 af0 = *(const short8*)(sA + r0 * 64 + (((kk * 4 + lq) ^ (r0 & 7)) * 8));
            short8 af1 = *(const short8*)(sA + r1 * 64 + (((kk * 4 + lq) ^ (r1 & 7)) * 8));
#pragma unroll
            for (int n2 = 0; n2 < 8; ++n2) {
                int r = n2 * 16 + lm;
                short8 bf = *(const short8*)(sB + r * 64 + (((kk * 4 + lq) ^ (r & 7)) * 8));
                acc[0][n2] = __builtin_amdgcn_mfma_f32_16x16x32_bf16(af0, bf, acc[0][n2], 0, 0, 0);
                acc[1][n2] = __builtin_amdgcn_mfma_f32_16x16x32_bf16(af1, bf, acc[1][n2], 0, 0, 0);
            }
        }
        __syncthreads();
    }

#pragma unroll
    for (int n2 = 0; n2 < 8; ++n2) {
        int dd = nt * 128 + n2 * 16 + lm;
        const float* rb = down_b + ((size_t)e * DIM + dd) * RANK;
        float rbv[RANK];
#pragma unroll
        for (int i = 0; i < RANK; ++i) rbv[i] = rb[i];
#pragma unroll
        for (int i = 0; i < 2; ++i) {
#pragma unroll
            for (int r = 0; r < 4; ++r) {
                int gg = mt * 128 + wv * 32 + i * 16 + lq * 4 + r;
                if (gg < cnt) {
                    int slot = off + gg;
                    int pp = sorted[slot];
                    const float* tv = t2 + (size_t)slot * RANK;
                    float val = acc[i][n2][r];
#pragma unroll
                    for (int j = 0; j < RANK; ++j) val += tv[j] * rbv[j];
                    atomicAdd(&out[(size_t)(pp >> 1) * DIM + dd], val * tw[pp]);
                }
            }
        }
    }
}

// ---------------------------------------------------------------------------
extern "C" void kernel_launch(void* const* d_in, const int* in_sizes, int n_in,
                              void* d_out, int out_size, void* d_ws, size_t ws_size,
                              hipStream_t stream) {
    const float* x      = (const float*)d_in[0];
    const float* tw     = (const float*)d_in[1];
    const int*   ids    = (const int*)d_in[2];
    const float* w_up   = (const float*)d_in[3];
    const float* w_down = (const float*)d_in[4];
    const float* up_a   = (const float*)d_in[5];
    const float* up_b   = (const float*)d_in[6];
    const float* down_a = (const float*)d_in[7];
    const float* down_b = (const float*)d_in[8];
    float* out = (float*)d_out;

    char* ws = (char*)d_ws;
    int*   offs   = (int*)ws;                               // 68 B
    int*   sorted = (int*)(ws + 4096);                      // 8 KB
    float* t_up   = (float*)(ws + 16384);                   // 128 KB
    float* t2     = (float*)(ws + 163840);                  // 128 KB
    unsigned short* act = (unsigned short*)(ws + 524288);   // 4 MB

    hipMemsetAsync(d_out, 0, (size_t)out_size * sizeof(float), stream);

    k_routing<<<1, 256, 0, stream>>>(ids, offs, sorted);
    k_tup<<<NPAIR, 64, 0, stream>>>(x, ids, up_a, t_up);

    dim3 gup(NEXP * 16, 16);
    k_up<<<gup, 256, 0, stream>>>(x, w_up, up_b, t_up, offs, sorted, act);

    k_t2<<<NPAIR, 64, 0, stream>>>(act, ids, sorted, down_a, t2);

    dim3 gdn(NEXP * 16, 16);
    k_down<<<gdn, 256, 0, stream>>>(act, w_down, ids, tw, down_b, t2, offs, sorted, out);
}

// Round 4
// 879.565 us; speedup vs baseline: 3.2948x; 3.2948x over previous
//
#include <hip/hip_runtime.h>
#include <hip/hip_bf16.h>
#include <math.h>

// Problem constants
#define N_TOK 1024
#define TOPK  2
#define NEXP  16
#define HID   1024   // H
#define DIM   2048   // D
#define RANK  16
#define NPAIR (N_TOK * TOPK)
#define MOE_SCALE 0.25f
#define MAXTILES 31  // sum_e ceil(cnt_e/128) <= 15 + 16

typedef __attribute__((ext_vector_type(8))) short short8;
typedef __attribute__((ext_vector_type(4))) float floatx4;

static __device__ __forceinline__ unsigned short f2bf(float f) {
    union { float f; unsigned int u; } v; v.f = f;
    unsigned int u = v.u;
    u += 0x7fffu + ((u >> 16) & 1u);   // RNE
    return (unsigned short)(u >> 16);
}

static __device__ __forceinline__ float bf2f(unsigned short s) {
    union { unsigned int u; float f; } v; v.u = ((unsigned int)s) << 16;
    return v.f;
}

static __device__ __forceinline__ short8 cvt8(float4 a, float4 b) {
    short8 o;
    o[0] = (short)f2bf(a.x); o[1] = (short)f2bf(a.y);
    o[2] = (short)f2bf(a.z); o[3] = (short)f2bf(a.w);
    o[4] = (short)f2bf(b.x); o[5] = (short)f2bf(b.y);
    o[6] = (short)f2bf(b.z); o[7] = (short)f2bf(b.w);
    return o;
}

// ---------------------------------------------------------------------------
// Kernel: routing — sort pair indices by expert + emit dense m-tile worklist.
// The worklist is the XCD fix: GEMM blocks index a compact list so active
// blocks are contiguous in linear dispatch order (spread over all 8 XCDs),
// instead of stride-16 blockIdx.x aliasing every worker onto XCD 0.
// ---------------------------------------------------------------------------
__global__ void k_routing(const int* __restrict__ ids,
                          int* __restrict__ offs,      // [NEXP+1]
                          int* __restrict__ sorted,    // [NPAIR]
                          int* __restrict__ tlist,     // [MAXTILES] (e<<8|mt)
                          int* __restrict__ tcount) {
    __shared__ int s_cnt[NEXP];
    __shared__ int s_off[NEXP + 1];
    int tid = threadIdx.x;
    if (tid < NEXP) s_cnt[tid] = 0;
    __syncthreads();
    for (int p = tid; p < NPAIR; p += blockDim.x) atomicAdd(&s_cnt[ids[p]], 1);
    __syncthreads();
    if (tid == 0) {
        int acc = 0;
        for (int e = 0; e < NEXP; ++e) { s_off[e] = acc; acc += s_cnt[e]; }
        s_off[NEXP] = acc;
        int t = 0;
        for (int e = 0; e < NEXP; ++e) {
            int c = s_off[e + 1] - s_off[e];
            for (int m = 0; m * 128 < c; ++m) tlist[t++] = (e << 8) | m;
        }
        *tcount = t;
    }
    __syncthreads();
    if (tid <= NEXP) offs[tid] = s_off[tid];
    if (tid < NEXP) s_cnt[tid] = s_off[tid];
    __syncthreads();
    for (int p = tid; p < NPAIR; p += blockDim.x) {
        int e = ids[p];
        int slot = atomicAdd(&s_cnt[e], 1);
        sorted[slot] = p;
    }
}

// ---------------------------------------------------------------------------
// Kernel: t_up[p][r] = SCALE * dot(x[n], up_a[e][r]).  One wave per pair.
// ---------------------------------------------------------------------------
__global__ void k_tup(const float* __restrict__ x, const int* __restrict__ ids,
                      const float* __restrict__ up_a, float* __restrict__ t_up) {
    int p = blockIdx.x;
    int lane = threadIdx.x;
    int n = p / TOPK;
    int e = ids[p];
    const float* xr = x + (size_t)n * DIM;
    const float* ar = up_a + (size_t)e * RANK * DIM;
    for (int r = 0; r < RANK; ++r) {
        const float* a = ar + (size_t)r * DIM;
        float s = 0.f;
        for (int d = lane; d < DIM; d += 64) s += xr[d] * a[d];
        for (int m = 32; m; m >>= 1) s += __shfl_xor(s, m, 64);
        if (lane == 0) t_up[(size_t)p * RANK + r] = MOE_SCALE * s;
    }
}

// ---------------------------------------------------------------------------
// Kernel: up-GEMM. Worklist-driven (e,mt); 128 tokens x 128 cols
// (64 gate + 64 mul), BK=64. In-register fp32->bf16, register prefetch.
// Epilogue: LoRA rank-16 + erf-gelu * mul -> act[slot][h] (bf16).
// ---------------------------------------------------------------------------
__global__ __launch_bounds__(256) void k_up(
        const float* __restrict__ x, const float* __restrict__ w_up,
        const float* __restrict__ up_b, const float* __restrict__ t_up,
        const int* __restrict__ offs, const int* __restrict__ sorted,
        const int* __restrict__ tlist, const int* __restrict__ tcount,
        unsigned short* __restrict__ act) {
    int wt = blockIdx.x;
    if (wt >= *tcount) return;
    int code = tlist[wt];
    int e = code >> 8, mt = code & 255;
    int nt = blockIdx.y;
    int off = offs[e], cnt = offs[e + 1] - off;

    __shared__ unsigned short sA[128 * 64];   // 16 KB, swizzled
    __shared__ unsigned short sB[128 * 64];   // 16 KB, swizzled

    int tid = threadIdx.x, lane = tid & 63, wv = tid >> 6;
    int lm = lane & 15, lq = lane >> 4;

    // staging: 2 threads per row, each 32 fp32 columns (128 B)
    int row  = tid >> 1;          // 0..127
    int hc   = (tid & 1) * 32;    // fp32 col offset within chunk

    int g = mt * 128 + row; if (g >= cnt) g = cnt - 1;   // clamp (dup rows ok)
    int p = sorted[off + g];
    const float* aptr = x + (size_t)(p >> 1) * DIM + hc;

    int wrow = (row < 64) ? (nt * 64 + row) : (HID + nt * 64 + (row - 64));
    const float* bptr = w_up + ((size_t)e * 2 * HID + wrow) * DIM + hc;

    floatx4 acc[2][8];
    floatx4 zero = {0.f, 0.f, 0.f, 0.f};
#pragma unroll
    for (int i = 0; i < 2; ++i)
#pragma unroll
        for (int j = 0; j < 8; ++j) acc[i][j] = zero;

    float4 pa[8], pb[8];
#pragma unroll
    for (int j = 0; j < 8; ++j) {
        pa[j] = *(const float4*)(aptr + 4 * j);
        pb[j] = *(const float4*)(bptr + 4 * j);
    }

    for (int kc = 0; kc < 32; ++kc) {
        // convert staged regs -> LDS (bf16, XOR-8 chunk swizzle)
#pragma unroll
        for (int c = 0; c < 4; ++c) {
            short8 va = cvt8(pa[2 * c], pa[2 * c + 1]);
            short8 vb = cvt8(pb[2 * c], pb[2 * c + 1]);
            int cl = (tid & 1) * 4 + c;
            *(short8*)(sA + row * 64 + ((cl ^ (row & 7)) * 8)) = va;
            *(short8*)(sB + row * 64 + ((cl ^ (row & 7)) * 8)) = vb;
        }
        __syncthreads();
        if (kc + 1 < 32) {   // prefetch next chunk; overlaps MFMA below
            const float* an = aptr + (kc + 1) * 64;
            const float* bn = bptr + (kc + 1) * 64;
#pragma unroll
            for (int j = 0; j < 8; ++j) {
                pa[j] = *(const float4*)(an + 4 * j);
                pb[j] = *(const float4*)(bn + 4 * j);
            }
        }
#pragma unroll
        for (int kk = 0; kk < 2; ++kk) {
            int r0 = wv * 32 + lm;
            int r1 = wv * 32 + 16 + lm;
            short8 af0 = *(const short8*)(sA + r0 * 64 + (((kk * 4 + lq) ^ (r0 & 7)) * 8));
            short8 af1 = *(const short8*)(sA + r1 * 64 + (((kk * 4 + lq) ^ (r1 & 7)) * 8));
#pragma unroll
            for (int n2 = 0; n2 < 8; ++n2) {
                int r = n2 * 16 + lm;
                short8 bf = *(const short8*)(sB + r * 64 + (((kk * 4 + lq) ^ (r & 7)) * 8));
                acc[0][n2] = __builtin_amdgcn_mfma_f32_16x16x32_bf16(af0, bf, acc[0][n2], 0, 0, 0);
                acc[1][n2] = __builtin_amdgcn_mfma_f32_16x16x32_bf16(af1, bf, acc[1][n2], 0, 0, 0);
            }
        }
        __syncthreads();
    }

    // epilogue: LoRA rank-16 + erf-gelu * mul -> act[slot][h]
    const float* upb = up_b + (size_t)e * 2 * HID * RANK;
#pragma unroll
    for (int n2 = 0; n2 < 4; ++n2) {
        int h = nt * 64 + n2 * 16 + lm;
        const float* b1 = upb + (size_t)h * RANK;
        const float* b2 = upb + (size_t)(h + HID) * RANK;
        float r1[RANK], r2[RANK];
#pragma unroll
        for (int i = 0; i < RANK; ++i) { r1[i] = b1[i]; r2[i] = b2[i]; }
#pragma unroll
        for (int i = 0; i < 2; ++i) {
#pragma unroll
            for (int r = 0; r < 4; ++r) {
                int gg = mt * 128 + wv * 32 + i * 16 + lq * 4 + r;
                if (gg < cnt) {
                    int slot = off + gg;
                    int pp = sorted[slot];
                    const float* tv = t_up + (size_t)pp * RANK;
                    float s1 = acc[i][n2][r], s2 = acc[i][n2 + 4][r];
#pragma unroll
                    for (int j = 0; j < RANK; ++j) { s1 += tv[j] * r1[j]; s2 += tv[j] * r2[j]; }
                    float gl = 0.5f * s1 * (1.f + erff(s1 * 0.70710678118654752f));
                    act[(size_t)slot * HID + h] = f2bf(gl * s2);
                }
            }
        }
    }
}

// ---------------------------------------------------------------------------
// Kernel: t2[slot][r] = SCALE * dot(act[slot], down_a[e][r]). One wave/slot.
// ---------------------------------------------------------------------------
__global__ void k_t2(const unsigned short* __restrict__ act,
                     const int* __restrict__ ids, const int* __restrict__ sorted,
                     const float* __restrict__ down_a, float* __restrict__ t2) {
    int s = blockIdx.x;
    int lane = threadIdx.x;
    int p = sorted[s];
    int e = ids[p];
    const unsigned short* ar = act + (size_t)s * HID;
    const float* da = down_a + (size_t)e * RANK * HID;
    float av[16];
#pragma unroll
    for (int i = 0; i < 16; ++i) av[i] = bf2f(ar[lane + i * 64]);
    for (int r = 0; r < RANK; ++r) {
        const float* a = da + (size_t)r * HID;
        float sum = 0.f;
#pragma unroll
        for (int i = 0; i < 16; ++i) sum += av[i] * a[lane + i * 64];
        for (int m = 32; m; m >>= 1) sum += __shfl_xor(sum, m, 64);
        if (lane == 0) t2[(size_t)s * RANK + r] = MOE_SCALE * sum;
    }
}

// ---------------------------------------------------------------------------
// Kernel: down-GEMM. Worklist-driven; 128 tokens x 128 d-rows, BK=64.
// A from act (bf16, ws), B from w_down (fp32) in-register convert + prefetch.
// Epilogue: LoRA + topk-weight + atomic scatter-add.
// ---------------------------------------------------------------------------
__global__ __launch_bounds__(256) void k_down(
        const unsigned short* __restrict__ act, const float* __restrict__ w_down,
        const int* __restrict__ ids, const float* __restrict__ tw,
        const float* __restrict__ down_b, const float* __restrict__ t2,
        const int* __restrict__ offs, const int* __restrict__ sorted,
        const int* __restrict__ tlist, const int* __restrict__ tcount,
        float* __restrict__ out) {
    int wt = blockIdx.x;
    if (wt >= *tcount) return;
    int code = tlist[wt];
    int e = code >> 8, mt = code & 255;
    int nt = blockIdx.y;
    int off = offs[e], cnt = offs[e + 1] - off;

    __shared__ unsigned short sA[128 * 64];
    __shared__ unsigned short sB[128 * 64];

    int tid = threadIdx.x, lane = tid & 63, wv = tid >> 6;
    int lm = lane & 15, lq = lane >> 4;

    int row = tid >> 1;           // 0..127
    int hcA = (tid & 1) * 32;     // bf16 col offset (A)
    int hcB = (tid & 1) * 32;     // fp32 col offset (B)

    int g = mt * 128 + row; if (g >= cnt) g = cnt - 1;
    const unsigned short* aptr = act + (size_t)(off + g) * HID + hcA;

    int d = nt * 128 + row;
    const float* bptr = w_down + ((size_t)e * DIM + d) * HID + hcB;

    floatx4 acc[2][8];
    floatx4 zero = {0.f, 0.f, 0.f, 0.f};
#pragma unroll
    for (int i = 0; i < 2; ++i)
#pragma unroll
        for (int j = 0; j < 8; ++j) acc[i][j] = zero;

    short8 pa[4];
    float4 pb[8];
#pragma unroll
    for (int j = 0; j < 4; ++j) pa[j] = *(const short8*)(aptr + 8 * j);
#pragma unroll
    for (int j = 0; j < 8; ++j) pb[j] = *(const float4*)(bptr + 4 * j);

    for (int kc = 0; kc < 16; ++kc) {
#pragma unroll
        for (int c = 0; c < 4; ++c) {
            short8 vb = cvt8(pb[2 * c], pb[2 * c + 1]);
            int cl = (tid & 1) * 4 + c;
            *(short8*)(sA + row * 64 + ((cl ^ (row & 7)) * 8)) = pa[c];
            *(short8*)(sB + row * 64 + ((cl ^ (row & 7)) * 8)) = vb;
        }
        __syncthreads();
        if (kc + 1 < 16) {
            const unsigned short* an = aptr + (kc + 1) * 64;
            const float* bn = bptr + (kc + 1) * 64;
#pragma unroll
            for (int j = 0; j < 4; ++j) pa[j] = *(const short8*)(an + 8 * j);
#pragma unroll
            for (int j = 0; j < 8; ++j) pb[j] = *(const float4*)(bn + 4 * j);
        }
#pragma unroll
        for (int kk = 0; kk < 2; ++kk) {
            int r0 = wv * 32 + lm;
            int r1 = wv * 32 + 16 + lm;
            short8 af0 = *(const short8*)(sA + r0 * 64 + (((kk * 4 + lq) ^ (r0 & 7)) * 8));
            short8 af1 = *(const short8*)(sA + r1 * 64 + (((kk * 4 + lq) ^ (r1 & 7)) * 8));
#pragma unroll
            for (int n2 = 0; n2 < 8; ++n2) {
                int r = n2 * 16 + lm;
                short8 bf = *(const short8*)(sB + r * 64 + (((kk * 4 + lq) ^ (r & 7)) * 8));
                acc[0][n2] = __builtin_amdgcn_mfma_f32_16x16x32_bf16(af0, bf, acc[0][n2], 0, 0, 0);
                acc[1][n2] = __builtin_amdgcn_mfma_f32_16x16x32_bf16(af1, bf, acc[1][n2], 0, 0, 0);
            }
        }
        __syncthreads();
    }

#pragma unroll
    for (int n2 = 0; n2 < 8; ++n2) {
        int dd = nt * 128 + n2 * 16 + lm;
        const float* rb = down_b + ((size_t)e * DIM + dd) * RANK;
        float rbv[RANK];
#pragma unroll
        for (int i = 0; i < RANK; ++i) rbv[i] = rb[i];
#pragma unroll
        for (int i = 0; i < 2; ++i) {
#pragma unroll
            for (int r = 0; r < 4; ++r) {
                int gg = mt * 128 + wv * 32 + i * 16 + lq * 4 + r;
                if (gg < cnt) {
                    int slot = off + gg;
                    int pp = sorted[slot];
                    const float* tv = t2 + (size_t)slot * RANK;
                    float val = acc[i][n2][r];
#pragma unroll
                    for (int j = 0; j < RANK; ++j) val += tv[j] * rbv[j];
                    atomicAdd(&out[(size_t)(pp >> 1) * DIM + dd], val * tw[pp]);
                }
            }
        }
    }
}

// ---------------------------------------------------------------------------
extern "C" void kernel_launch(void* const* d_in, const int* in_sizes, int n_in,
                              void* d_out, int out_size, void* d_ws, size_t ws_size,
                              hipStream_t stream) {
    const float* x      = (const float*)d_in[0];
    const float* tw     = (const float*)d_in[1];
    const int*   ids    = (const int*)d_in[2];
    const float* w_up   = (const float*)d_in[3];
    const float* w_down = (const float*)d_in[4];
    const float* up_a   = (const float*)d_in[5];
    const float* up_b   = (const float*)d_in[6];
    const float* down_a = (const float*)d_in[7];
    const float* down_b = (const float*)d_in[8];
    float* out = (float*)d_out;

    char* ws = (char*)d_ws;
    int*   offs   = (int*)ws;                               // 68 B
    int*   tlist  = (int*)(ws + 1024);                      // 124 B
    int*   tcount = (int*)(ws + 2048);                      // 4 B
    int*   sorted = (int*)(ws + 4096);                      // 8 KB
    float* t_up   = (float*)(ws + 16384);                   // 128 KB
    float* t2     = (float*)(ws + 163840);                  // 128 KB
    unsigned short* act = (unsigned short*)(ws + 524288);   // 4 MB

    hipMemsetAsync(d_out, 0, (size_t)out_size * sizeof(float), stream);

    k_routing<<<1, 256, 0, stream>>>(ids, offs, sorted, tlist, tcount);
    k_tup<<<NPAIR, 64, 0, stream>>>(x, ids, up_a, t_up);

    dim3 gup(MAXTILES, 16);
    k_up<<<gup, 256, 0, stream>>>(x, w_up, up_b, t_up, offs, sorted, tlist, tcount, act);

    k_t2<<<NPAIR, 64, 0, stream>>>(act, ids, sorted, down_a, t2);

    dim3 gdn(MAXTILES, 16);
    k_down<<<gdn, 256, 0, stream>>>(act, w_down, ids, tw, down_b, t2, offs, sorted, tlist, tcount, out);
}